// Round 2
// baseline (418.696 us; speedup 1.0000x reference)
//
#include <hip/hip_runtime.h>
#include <hip/hip_bf16.h>

#define NN 32
#define CC 16
#define HH 256
#define WW 256
#define HWSZ (HH * WW)

// Native clang vector types — required by __builtin_nontemporal_load/store
// (HIP's float4/float2 are structs and are rejected by the builtin).
typedef float  f32x4 __attribute__((ext_vector_type(4)));
typedef float  f32x2 __attribute__((ext_vector_type(2)));

// ---------- Transpose + downconvert: NCHW fp32 -> NHWC bf16 (into ws) ----------
// 4 consecutive x-pixels per thread: float4 reads per channel (coalesced,
// 1 KB/wave/instr), 128 B contiguous bf16 write per thread.
// Input is read exactly once -> non-temporal loads (don't pollute L2).
// Output IS re-read by the sample kernel -> normal (cacheable) stores so it
// lands in L3.
__global__ __launch_bounds__(256) void nchw_to_nhwc_bf16_kernel(
    const float* __restrict__ inp,
    __hip_bfloat16* __restrict__ dst)
{
    int t = blockIdx.x * blockDim.x + threadIdx.x;   // 0 .. N*H*W/4 - 1
    int pix = t * 4;
    int x = pix & (WW - 1);
    int y = (pix >> 8) & (HH - 1);
    int n = pix >> 16;

    const float* src = inp + (size_t)n * CC * HWSZ + y * WW + x;
    f32x4 v[CC];
#pragma unroll
    for (int c = 0; c < CC; ++c)
        v[c] = __builtin_nontemporal_load((const f32x4*)(src + (size_t)c * HWSZ));

#pragma unroll
    for (int j = 0; j < 4; ++j) {
        union {
            __hip_bfloat16 h[CC];
            uint4 q[2];
        } u;
        const float* vf = (const float*)v;  // v[c] component j = vf[4*c + j]
#pragma unroll
        for (int c = 0; c < CC; ++c)
            u.h[c] = __float2bfloat16(vf[4 * c + j]);
        uint4* d = (uint4*)(dst + (size_t)(pix + j) * CC);
        d[0] = u.q[0];
        d[1] = u.q[1];
    }
}

// ---------- Sample from NHWC bf16 ----------
// Key change vs baseline: ALL 8 corner loads (4 corners x 32 B) are issued
// before any unpack/FMA, fenced with sched_barrier(0) so the compiler cannot
// re-serialize them to save registers. This raises per-thread memory
// parallelism from ~2 in-flight loads to 8, attacking the gather-latency
// bottleneck (VALUBusy 6.5%, HBM 47% => latency-bound).
// Output is write-once streaming -> non-temporal stores (keep L2 for table).
__global__ __launch_bounds__(256) void sample_nhwc_bf16_kernel(
    const __hip_bfloat16* __restrict__ src,    // NHWC bf16
    const float* __restrict__ grid,
    const int*   __restrict__ idx,
    float*       __restrict__ out,
    int P)
{
    int p = blockIdx.x * blockDim.x + threadIdx.x;
    if (p >= P) return;

    f32x2 g = __builtin_nontemporal_load((const f32x2*)grid + p);
    int b   = __builtin_nontemporal_load(idx + p);

    float x = (g.x + 1.0f) * 0.5f * (float)(WW - 1);
    float y = (g.y + 1.0f) * 0.5f * (float)(HH - 1);

    float x0f = floorf(x);
    float y0f = floorf(y);
    float wx = x - x0f;
    float wy = y - y0f;

    int x0 = (int)x0f, y0 = (int)y0f;
    int x1 = x0 + 1, y1 = y0 + 1;

    float vx0 = (x0 >= 0 && x0 <= WW - 1) ? 1.0f : 0.0f;
    float vx1 = (x1 >= 0 && x1 <= WW - 1) ? 1.0f : 0.0f;
    float vy0 = (y0 >= 0 && y0 <= HH - 1) ? 1.0f : 0.0f;
    float vy1 = (y1 >= 0 && y1 <= HH - 1) ? 1.0f : 0.0f;

    int x0c = min(max(x0, 0), WW - 1);
    int x1c = min(max(x1, 0), WW - 1);
    int y0c = min(max(y0, 0), HH - 1);
    int y1c = min(max(y1, 0), HH - 1);

    float w00 = (1.0f - wx) * (1.0f - wy) * vx0 * vy0;
    float w01 = wx * (1.0f - wy) * vx1 * vy0;
    float w10 = (1.0f - wx) * wy * vx0 * vy1;
    float w11 = wx * wy * vx1 * vy1;

    const __hip_bfloat16* base = src + (size_t)b * (size_t)(HWSZ * CC);
    const uint4* c00 = (const uint4*)(base + (uint32_t)(y0c * WW + x0c) * CC);
    const uint4* c01 = (const uint4*)(base + (uint32_t)(y0c * WW + x1c) * CC);
    const uint4* c10 = (const uint4*)(base + (uint32_t)(y1c * WW + x0c) * CC);
    const uint4* c11 = (const uint4*)(base + (uint32_t)(y1c * WW + x1c) * CC);

    // Issue all 8 16-B loads back-to-back.
    uint4 q0 = c00[0];
    uint4 q1 = c00[1];
    uint4 q2 = c01[0];
    uint4 q3 = c01[1];
    uint4 q4 = c10[0];
    uint4 q5 = c10[1];
    uint4 q6 = c11[0];
    uint4 q7 = c11[1];
    // Scheduling fence: nothing below may be hoisted above, nothing above may
    // sink below -> all 8 global_load_dwordx4 are issued before first use.
    __builtin_amdgcn_sched_barrier(0);

    float res[CC];
#pragma unroll
    for (int i = 0; i < CC; ++i) res[i] = 0.0f;

    auto acc = [&](uint4 a, uint4 bq, float w) {
        uint32_t u[8] = {a.x, a.y, a.z, a.w, bq.x, bq.y, bq.z, bq.w};
#pragma unroll
        for (int i = 0; i < 8; ++i) {
            __hip_bfloat162 h2 = *reinterpret_cast<__hip_bfloat162*>(&u[i]);
            float2 f = __bfloat1622float2(h2);
            res[2 * i + 0] += f.x * w;
            res[2 * i + 1] += f.y * w;
        }
    };

    acc(q0, q1, w00);
    acc(q2, q3, w01);
    acc(q4, q5, w10);
    acc(q6, q7, w11);

    f32x4* outv = (f32x4*)(out + (size_t)p * CC);
#pragma unroll
    for (int i = 0; i < 4; ++i) {
        f32x4 o = {res[4 * i + 0], res[4 * i + 1], res[4 * i + 2], res[4 * i + 3]};
        __builtin_nontemporal_store(o, outv + i);
    }
}

// ---------- Fallback (NCHW direct, no workspace needed) ----------
__global__ __launch_bounds__(256) void sample_nchw_kernel(
    const float* __restrict__ inp,
    const float* __restrict__ grid,
    const int*   __restrict__ idx,
    float*       __restrict__ out,
    int P)
{
    int p = blockIdx.x * blockDim.x + threadIdx.x;
    if (p >= P) return;

    float2 g = ((const float2*)grid)[p];
    float x = (g.x + 1.0f) * 0.5f * (float)(WW - 1);
    float y = (g.y + 1.0f) * 0.5f * (float)(HH - 1);

    float x0f = floorf(x), y0f = floorf(y);
    float wx = x - x0f, wy = y - y0f;
    int x0 = (int)x0f, y0 = (int)y0f, x1 = x0 + 1, y1 = y0 + 1;

    float vx0 = (x0 >= 0 && x0 <= WW - 1) ? 1.0f : 0.0f;
    float vx1 = (x1 >= 0 && x1 <= WW - 1) ? 1.0f : 0.0f;
    float vy0 = (y0 >= 0 && y0 <= HH - 1) ? 1.0f : 0.0f;
    float vy1 = (y1 >= 0 && y1 <= HH - 1) ? 1.0f : 0.0f;

    int x0c = min(max(x0, 0), WW - 1);
    int x1c = min(max(x1, 0), WW - 1);
    int y0c = min(max(y0, 0), HH - 1);
    int y1c = min(max(y1, 0), HH - 1);

    float w00 = (1.0f - wx) * (1.0f - wy) * vx0 * vy0;
    float w01 = wx * (1.0f - wy) * vx1 * vy0;
    float w10 = (1.0f - wx) * wy * vx0 * vy1;
    float w11 = wx * wy * vx1 * vy1;

    const float* base = inp + (size_t)idx[p] * (size_t)(CC * HWSZ);
    int o00 = y0c * WW + x0c, o01 = y0c * WW + x1c;
    int o10 = y1c * WW + x0c, o11 = y1c * WW + x1c;

    float res[CC];
#pragma unroll
    for (int c = 0; c < CC; ++c) {
        const float* bsrc = base + c * HWSZ;
        res[c] = bsrc[o00] * w00 + bsrc[o01] * w01 + bsrc[o10] * w10 + bsrc[o11] * w11;
    }
    float4* outv = (float4*)(out + (size_t)p * CC);
#pragma unroll
    for (int i = 0; i < 4; ++i)
        outv[i] = make_float4(res[4 * i], res[4 * i + 1], res[4 * i + 2], res[4 * i + 3]);
}

extern "C" void kernel_launch(void* const* d_in, const int* in_sizes, int n_in,
                              void* d_out, int out_size, void* d_ws, size_t ws_size,
                              hipStream_t stream) {
    const float* inp  = (const float*)d_in[0];
    const float* grid = (const float*)d_in[1];
    const int*   idx  = (const int*)d_in[2];
    float* out = (float*)d_out;

    int P = in_sizes[2];
    const size_t needed = (size_t)NN * CC * HWSZ * sizeof(__hip_bfloat16);  // 64 MiB

    if (ws_size >= needed) {
        __hip_bfloat16* nhwc = (__hip_bfloat16*)d_ws;
        int tquads = NN * HH * WW / 4;
        nchw_to_nhwc_bf16_kernel<<<tquads / 256, 256, 0, stream>>>(inp, nhwc);
        sample_nhwc_bf16_kernel<<<(P + 255) / 256, 256, 0, stream>>>(nhwc, grid, idx, out, P);
    } else {
        sample_nchw_kernel<<<(P + 255) / 256, 256, 0, stream>>>(inp, grid, idx, out, P);
    }
}

// Round 3
// 371.572 us; speedup vs baseline: 1.1268x; 1.1268x over previous
//
#include <hip/hip_runtime.h>
#include <hip/hip_bf16.h>

#define NN 32
#define CC 16
#define HH 256
#define WW 256
#define HWSZ (HH * WW)

// Native clang vector types — required by __builtin_nontemporal_load/store
// (HIP's float4/float2 are structs and are rejected by the builtin).
typedef float f32x4 __attribute__((ext_vector_type(4)));
typedef float f32x2 __attribute__((ext_vector_type(2)));
typedef int   i32x2 __attribute__((ext_vector_type(2)));

// ---------- Transpose + downconvert: NCHW fp32 -> NHWC bf16 (into ws) ----------
// 4 consecutive x-pixels per thread: float4 reads per channel (coalesced,
// 1 KB/wave/instr), 128 B contiguous bf16 write per thread.
// Input read exactly once -> non-temporal loads (don't pollute L2).
// Output IS re-read by the sample kernel -> cached stores (land in L2/L3).
__global__ __launch_bounds__(256) void nchw_to_nhwc_bf16_kernel(
    const float* __restrict__ inp,
    __hip_bfloat16* __restrict__ dst)
{
    int t = blockIdx.x * blockDim.x + threadIdx.x;   // 0 .. N*H*W/4 - 1
    int pix = t * 4;
    int x = pix & (WW - 1);
    int y = (pix >> 8) & (HH - 1);
    int n = pix >> 16;

    const float* src = inp + (size_t)n * CC * HWSZ + y * WW + x;
    f32x4 v[CC];
#pragma unroll
    for (int c = 0; c < CC; ++c)
        v[c] = __builtin_nontemporal_load((const f32x4*)(src + (size_t)c * HWSZ));

#pragma unroll
    for (int j = 0; j < 4; ++j) {
        union {
            __hip_bfloat16 h[CC];
            uint4 q[2];
        } u;
        const float* vf = (const float*)v;  // v[c] component j = vf[4*c + j]
#pragma unroll
        for (int c = 0; c < CC; ++c)
            u.h[c] = __float2bfloat16(vf[4 * c + j]);
        uint4* d = (uint4*)(dst + (size_t)(pix + j) * CC);
        d[0] = u.q[0];
        d[1] = u.q[1];
    }
}

// ---------- Sample from NHWC bf16, 2 points per thread ----------
// Latency-bound gather (VALUBusy ~4-6%, MfmaUtil 0, HBM <50%): the lever is
// memory-level parallelism. Each thread computes addresses for TWO points and
// issues all 16 global_load_dwordx4 back-to-back (sched_barrier(0) fence so
// the compiler cannot re-serialize them to save VGPRs), then unpacks/FMAs.
// Stores are CACHED (nt-stores broke L2 write-combining: WRITE_SIZE 125->305MB).
__global__ __launch_bounds__(256) void sample_nhwc_bf16_x2_kernel(
    const __hip_bfloat16* __restrict__ src,    // NHWC bf16
    const float* __restrict__ grid,
    const int*   __restrict__ idx,
    float*       __restrict__ out,
    int P)
{
    int t = blockIdx.x * blockDim.x + threadIdx.x;
    int p0 = t * 2;
    if (p0 >= P) return;
    bool has2 = (p0 + 1) < P;

    // grid coords for both points: one 16-B load (p0 is even -> aligned).
    f32x4 g;
    if (has2) {
        g = __builtin_nontemporal_load((const f32x4*)(grid + 2 * p0));
    } else {
        f32x2 g0 = __builtin_nontemporal_load((const f32x2*)(grid + 2 * p0));
        g.x = g0.x; g.y = g0.y; g.z = g0.x; g.w = g0.y;
    }
    i32x2 bb;
    if (has2) {
        bb = __builtin_nontemporal_load((const i32x2*)(idx + p0));
    } else {
        bb.x = idx[p0]; bb.y = bb.x;
    }

    const uint4* cptr[8];
    float wgt[8];

#pragma unroll
    for (int j = 0; j < 2; ++j) {
        float gx = (j == 0) ? g.x : g.z;
        float gy = (j == 0) ? g.y : g.w;
        float x = (gx + 1.0f) * 0.5f * (float)(WW - 1);
        float y = (gy + 1.0f) * 0.5f * (float)(HH - 1);

        float x0f = floorf(x), y0f = floorf(y);
        float wx = x - x0f, wy = y - y0f;
        int x0 = (int)x0f, y0 = (int)y0f;
        int x1 = x0 + 1, y1 = y0 + 1;

        float vx0 = (x0 >= 0 && x0 <= WW - 1) ? 1.0f : 0.0f;
        float vx1 = (x1 >= 0 && x1 <= WW - 1) ? 1.0f : 0.0f;
        float vy0 = (y0 >= 0 && y0 <= HH - 1) ? 1.0f : 0.0f;
        float vy1 = (y1 >= 0 && y1 <= HH - 1) ? 1.0f : 0.0f;

        int x0c = min(max(x0, 0), WW - 1);
        int x1c = min(max(x1, 0), WW - 1);
        int y0c = min(max(y0, 0), HH - 1);
        int y1c = min(max(y1, 0), HH - 1);

        int b = (j == 0) ? bb.x : bb.y;
        const __hip_bfloat16* base = src + (size_t)b * (size_t)(HWSZ * CC);

        cptr[j * 4 + 0] = (const uint4*)(base + (uint32_t)(y0c * WW + x0c) * CC);
        cptr[j * 4 + 1] = (const uint4*)(base + (uint32_t)(y0c * WW + x1c) * CC);
        cptr[j * 4 + 2] = (const uint4*)(base + (uint32_t)(y1c * WW + x0c) * CC);
        cptr[j * 4 + 3] = (const uint4*)(base + (uint32_t)(y1c * WW + x1c) * CC);

        wgt[j * 4 + 0] = (1.0f - wx) * (1.0f - wy) * vx0 * vy0;
        wgt[j * 4 + 1] = wx * (1.0f - wy) * vx1 * vy0;
        wgt[j * 4 + 2] = (1.0f - wx) * wy * vx0 * vy1;
        wgt[j * 4 + 3] = wx * wy * vx1 * vy1;
    }

    // Issue ALL 16 16-B loads back-to-back: 16 in-flight gathers per thread.
    uint4 q[16];
#pragma unroll
    for (int k = 0; k < 8; ++k) {
        q[2 * k + 0] = cptr[k][0];
        q[2 * k + 1] = cptr[k][1];
    }
    // Fence: nothing below may be hoisted above -> all 16 global_load_dwordx4
    // are issued before the first waitcnt/use.
    __builtin_amdgcn_sched_barrier(0);

#pragma unroll
    for (int j = 0; j < 2; ++j) {
        float res[CC];
#pragma unroll
        for (int i = 0; i < CC; ++i) res[i] = 0.0f;

#pragma unroll
        for (int k = 0; k < 4; ++k) {
            float w = wgt[j * 4 + k];
            uint32_t u[8];
            uint4 a = q[j * 8 + 2 * k + 0];
            uint4 bq = q[j * 8 + 2 * k + 1];
            u[0] = a.x; u[1] = a.y; u[2] = a.z; u[3] = a.w;
            u[4] = bq.x; u[5] = bq.y; u[6] = bq.z; u[7] = bq.w;
#pragma unroll
            for (int i = 0; i < 8; ++i) {
                __hip_bfloat162 h2 = *reinterpret_cast<__hip_bfloat162*>(&u[i]);
                float2 f = __bfloat1622float2(h2);
                res[2 * i + 0] += f.x * w;
                res[2 * i + 1] += f.y * w;
            }
        }

        int p = p0 + j;
        if (j == 0 || has2) {
            float4* outv = (float4*)(out + (size_t)p * CC);
#pragma unroll
            for (int i = 0; i < 4; ++i)
                outv[i] = make_float4(res[4 * i + 0], res[4 * i + 1],
                                      res[4 * i + 2], res[4 * i + 3]);
        }
    }
}

// ---------- Fallback (NCHW direct, no workspace needed) ----------
__global__ __launch_bounds__(256) void sample_nchw_kernel(
    const float* __restrict__ inp,
    const float* __restrict__ grid,
    const int*   __restrict__ idx,
    float*       __restrict__ out,
    int P)
{
    int p = blockIdx.x * blockDim.x + threadIdx.x;
    if (p >= P) return;

    float2 g = ((const float2*)grid)[p];
    float x = (g.x + 1.0f) * 0.5f * (float)(WW - 1);
    float y = (g.y + 1.0f) * 0.5f * (float)(HH - 1);

    float x0f = floorf(x), y0f = floorf(y);
    float wx = x - x0f, wy = y - y0f;
    int x0 = (int)x0f, y0 = (int)y0f, x1 = x0 + 1, y1 = y0 + 1;

    float vx0 = (x0 >= 0 && x0 <= WW - 1) ? 1.0f : 0.0f;
    float vx1 = (x1 >= 0 && x1 <= WW - 1) ? 1.0f : 0.0f;
    float vy0 = (y0 >= 0 && y0 <= HH - 1) ? 1.0f : 0.0f;
    float vy1 = (y1 >= 0 && y1 <= HH - 1) ? 1.0f : 0.0f;

    int x0c = min(max(x0, 0), WW - 1);
    int x1c = min(max(x1, 0), WW - 1);
    int y0c = min(max(y0, 0), HH - 1);
    int y1c = min(max(y1, 0), HH - 1);

    float w00 = (1.0f - wx) * (1.0f - wy) * vx0 * vy0;
    float w01 = wx * (1.0f - wy) * vx1 * vy0;
    float w10 = (1.0f - wx) * wy * vx0 * vy1;
    float w11 = wx * wy * vx1 * vy1;

    const float* base = inp + (size_t)idx[p] * (size_t)(CC * HWSZ);
    int o00 = y0c * WW + x0c, o01 = y0c * WW + x1c;
    int o10 = y1c * WW + x0c, o11 = y1c * WW + x1c;

    float res[CC];
#pragma unroll
    for (int c = 0; c < CC; ++c) {
        const float* bsrc = base + c * HWSZ;
        res[c] = bsrc[o00] * w00 + bsrc[o01] * w01 + bsrc[o10] * w10 + bsrc[o11] * w11;
    }
    float4* outv = (float4*)(out + (size_t)p * CC);
#pragma unroll
    for (int i = 0; i < 4; ++i)
        outv[i] = make_float4(res[4 * i], res[4 * i + 1], res[4 * i + 2], res[4 * i + 3]);
}

extern "C" void kernel_launch(void* const* d_in, const int* in_sizes, int n_in,
                              void* d_out, int out_size, void* d_ws, size_t ws_size,
                              hipStream_t stream) {
    const float* inp  = (const float*)d_in[0];
    const float* grid = (const float*)d_in[1];
    const int*   idx  = (const int*)d_in[2];
    float* out = (float*)d_out;

    int P = in_sizes[2];
    const size_t needed = (size_t)NN * CC * HWSZ * sizeof(__hip_bfloat16);  // 64 MiB

    if (ws_size >= needed) {
        __hip_bfloat16* nhwc = (__hip_bfloat16*)d_ws;
        int tquads = NN * HH * WW / 4;
        nchw_to_nhwc_bf16_kernel<<<tquads / 256, 256, 0, stream>>>(inp, nhwc);
        int nthreads = (P + 1) / 2;
        sample_nhwc_bf16_x2_kernel<<<(nthreads + 255) / 256, 256, 0, stream>>>(nhwc, grid, idx, out, P);
    } else {
        sample_nchw_kernel<<<(P + 255) / 256, 256, 0, stream>>>(inp, grid, idx, out, P);
    }
}

// Round 4
// 337.574 us; speedup vs baseline: 1.2403x; 1.1007x over previous
//
#include <hip/hip_runtime.h>
#include <hip/hip_bf16.h>

#define NN 32
#define CC 16
#define HH 256
#define WW 256
#define HWSZ (HH * WW)

// Native clang vector type — required by __builtin_nontemporal_load
// (HIP's float4 is a struct and is rejected by the builtin).
typedef float f32x4 __attribute__((ext_vector_type(4)));

// ---------- Transpose + downconvert: NCHW fp32 -> NHWC bf16 (into ws) ----------
// 4 consecutive x-pixels per thread: float4 reads per channel (coalesced,
// 1 KB/wave/instr), 128 B contiguous bf16 write per thread.
// Input read exactly once -> non-temporal loads (don't displace the table
// from L2/L3). Output IS re-read by the sample kernel -> cached stores.
__global__ __launch_bounds__(256) void nchw_to_nhwc_bf16_kernel(
    const float* __restrict__ inp,
    __hip_bfloat16* __restrict__ dst)
{
    int t = blockIdx.x * blockDim.x + threadIdx.x;   // 0 .. N*H*W/4 - 1
    int pix = t * 4;
    int x = pix & (WW - 1);
    int y = (pix >> 8) & (HH - 1);
    int n = pix >> 16;

    const float* src = inp + (size_t)n * CC * HWSZ + y * WW + x;
    f32x4 v[CC];
#pragma unroll
    for (int c = 0; c < CC; ++c)
        v[c] = __builtin_nontemporal_load((const f32x4*)(src + (size_t)c * HWSZ));

#pragma unroll
    for (int j = 0; j < 4; ++j) {
        union {
            __hip_bfloat16 h[CC];
            uint4 q[2];
        } u;
        const float* vf = (const float*)v;  // v[c] component j = vf[4*c + j]
#pragma unroll
        for (int c = 0; c < CC; ++c)
            u.h[c] = __float2bfloat16(vf[4 * c + j]);
        uint4* d = (uint4*)(dst + (size_t)(pix + j) * CC);
        d[0] = u.q[0];
        d[1] = u.q[1];
    }
}

// ---------- Sample from NHWC bf16, 1 point per thread ----------
// Round-0 structure (117 us, occupancy 75%) with EXACTLY ONE change:
// all 8 corner loads (4 corners x 32 B) are issued back-to-back and fenced
// with sched_barrier(0), so the thread has 8 gathers in flight instead of
// ~2 (the compiler's serialized load->consume order). Everything else
// (cached grid/idx loads, cached output stores) matches round 0 — the
// nt-store experiment showed cached stores are required for L2 write
// combining (WRITE_SIZE 125 MB vs 305 MB).
__global__ __launch_bounds__(256) void sample_nhwc_bf16_kernel(
    const __hip_bfloat16* __restrict__ src,    // NHWC bf16
    const float* __restrict__ grid,
    const int*   __restrict__ idx,
    float*       __restrict__ out,
    int P)
{
    int p = blockIdx.x * blockDim.x + threadIdx.x;
    if (p >= P) return;

    float2 g = ((const float2*)grid)[p];
    int b = idx[p];

    float x = (g.x + 1.0f) * 0.5f * (float)(WW - 1);
    float y = (g.y + 1.0f) * 0.5f * (float)(HH - 1);

    float x0f = floorf(x);
    float y0f = floorf(y);
    float wx = x - x0f;
    float wy = y - y0f;

    int x0 = (int)x0f, y0 = (int)y0f;
    int x1 = x0 + 1, y1 = y0 + 1;

    float vx0 = (x0 >= 0 && x0 <= WW - 1) ? 1.0f : 0.0f;
    float vx1 = (x1 >= 0 && x1 <= WW - 1) ? 1.0f : 0.0f;
    float vy0 = (y0 >= 0 && y0 <= HH - 1) ? 1.0f : 0.0f;
    float vy1 = (y1 >= 0 && y1 <= HH - 1) ? 1.0f : 0.0f;

    int x0c = min(max(x0, 0), WW - 1);
    int x1c = min(max(x1, 0), WW - 1);
    int y0c = min(max(y0, 0), HH - 1);
    int y1c = min(max(y1, 0), HH - 1);

    float w00 = (1.0f - wx) * (1.0f - wy) * vx0 * vy0;
    float w01 = wx * (1.0f - wy) * vx1 * vy0;
    float w10 = (1.0f - wx) * wy * vx0 * vy1;
    float w11 = wx * wy * vx1 * vy1;

    const __hip_bfloat16* base = src + (size_t)b * (size_t)(HWSZ * CC);
    const uint4* c00 = (const uint4*)(base + (uint32_t)(y0c * WW + x0c) * CC);
    const uint4* c01 = (const uint4*)(base + (uint32_t)(y0c * WW + x1c) * CC);
    const uint4* c10 = (const uint4*)(base + (uint32_t)(y1c * WW + x0c) * CC);
    const uint4* c11 = (const uint4*)(base + (uint32_t)(y1c * WW + x1c) * CC);

    // Issue all 8 16-B loads back-to-back: 8 in-flight gathers per thread.
    uint4 q0 = c00[0];
    uint4 q1 = c00[1];
    uint4 q2 = c01[0];
    uint4 q3 = c01[1];
    uint4 q4 = c10[0];
    uint4 q5 = c10[1];
    uint4 q6 = c11[0];
    uint4 q7 = c11[1];
    // Scheduling fence: the unpack/FMA below may not be hoisted above ->
    // all 8 global_load_dwordx4 are issued before the first vmcnt wait.
    __builtin_amdgcn_sched_barrier(0);

    float res[CC];
#pragma unroll
    for (int i = 0; i < CC; ++i) res[i] = 0.0f;

    auto acc = [&](uint4 a, uint4 bq, float w) {
        uint32_t u[8] = {a.x, a.y, a.z, a.w, bq.x, bq.y, bq.z, bq.w};
#pragma unroll
        for (int i = 0; i < 8; ++i) {
            __hip_bfloat162 h2 = *reinterpret_cast<__hip_bfloat162*>(&u[i]);
            float2 f = __bfloat1622float2(h2);
            res[2 * i + 0] += f.x * w;
            res[2 * i + 1] += f.y * w;
        }
    };

    acc(q0, q1, w00);
    acc(q2, q3, w01);
    acc(q4, q5, w10);
    acc(q6, q7, w11);

    float4* outv = (float4*)(out + (size_t)p * CC);
#pragma unroll
    for (int i = 0; i < 4; ++i)
        outv[i] = make_float4(res[4 * i + 0], res[4 * i + 1],
                              res[4 * i + 2], res[4 * i + 3]);
}

// ---------- Fallback (NCHW direct, no workspace needed) ----------
__global__ __launch_bounds__(256) void sample_nchw_kernel(
    const float* __restrict__ inp,
    const float* __restrict__ grid,
    const int*   __restrict__ idx,
    float*       __restrict__ out,
    int P)
{
    int p = blockIdx.x * blockDim.x + threadIdx.x;
    if (p >= P) return;

    float2 g = ((const float2*)grid)[p];
    float x = (g.x + 1.0f) * 0.5f * (float)(WW - 1);
    float y = (g.y + 1.0f) * 0.5f * (float)(HH - 1);

    float x0f = floorf(x), y0f = floorf(y);
    float wx = x - x0f, wy = y - y0f;
    int x0 = (int)x0f, y0 = (int)y0f, x1 = x0 + 1, y1 = y0 + 1;

    float vx0 = (x0 >= 0 && x0 <= WW - 1) ? 1.0f : 0.0f;
    float vx1 = (x1 >= 0 && x1 <= WW - 1) ? 1.0f : 0.0f;
    float vy0 = (y0 >= 0 && y0 <= HH - 1) ? 1.0f : 0.0f;
    float vy1 = (y1 >= 0 && y1 <= HH - 1) ? 1.0f : 0.0f;

    int x0c = min(max(x0, 0), WW - 1);
    int x1c = min(max(x1, 0), WW - 1);
    int y0c = min(max(y0, 0), HH - 1);
    int y1c = min(max(y1, 0), HH - 1);

    float w00 = (1.0f - wx) * (1.0f - wy) * vx0 * vy0;
    float w01 = wx * (1.0f - wy) * vx1 * vy0;
    float w10 = (1.0f - wx) * wy * vx0 * vy1;
    float w11 = wx * wy * vx1 * vy1;

    const float* base = inp + (size_t)idx[p] * (size_t)(CC * HWSZ);
    int o00 = y0c * WW + x0c, o01 = y0c * WW + x1c;
    int o10 = y1c * WW + x0c, o11 = y1c * WW + x1c;

    float res[CC];
#pragma unroll
    for (int c = 0; c < CC; ++c) {
        const float* bsrc = base + c * HWSZ;
        res[c] = bsrc[o00] * w00 + bsrc[o01] * w01 + bsrc[o10] * w10 + bsrc[o11] * w11;
    }
    float4* outv = (float4*)(out + (size_t)p * CC);
#pragma unroll
    for (int i = 0; i < 4; ++i)
        outv[i] = make_float4(res[4 * i], res[4 * i + 1], res[4 * i + 2], res[4 * i + 3]);
}

extern "C" void kernel_launch(void* const* d_in, const int* in_sizes, int n_in,
                              void* d_out, int out_size, void* d_ws, size_t ws_size,
                              hipStream_t stream) {
    const float* inp  = (const float*)d_in[0];
    const float* grid = (const float*)d_in[1];
    const int*   idx  = (const int*)d_in[2];
    float* out = (float*)d_out;

    int P = in_sizes[2];
    const size_t needed = (size_t)NN * CC * HWSZ * sizeof(__hip_bfloat16);  // 64 MiB

    if (ws_size >= needed) {
        __hip_bfloat16* nhwc = (__hip_bfloat16*)d_ws;
        int tquads = NN * HH * WW / 4;
        nchw_to_nhwc_bf16_kernel<<<tquads / 256, 256, 0, stream>>>(inp, nhwc);
        sample_nhwc_bf16_kernel<<<(P + 255) / 256, 256, 0, stream>>>(nhwc, grid, idx, out, P);
    } else {
        sample_nchw_kernel<<<(P + 255) / 256, 256, 0, stream>>>(inp, grid, idx, out, P);
    }
}